// Round 7
// baseline (887.322 us; speedup 1.0000x reference)
//
#include <hip/hip_runtime.h>
#include <hip/hip_bf16.h>

#define IN_F 4096
#define OUT_F 11008
#define GSIZE 128
#define M_TOTAL 8192

typedef float f32x4 __attribute__((ext_vector_type(4)));
typedef float f32x16 __attribute__((ext_vector_type(16)));
typedef unsigned short u16x8 __attribute__((ext_vector_type(8)));
typedef unsigned int u32x4 __attribute__((ext_vector_type(4)));
typedef __bf16 bf16x8 __attribute__((ext_vector_type(8)));

#define ASG __attribute__((address_space(1)))
#define ASL __attribute__((address_space(3)))

__device__ __forceinline__ unsigned short f2bf(float f) {
    union { float f; unsigned int u; } v;
    v.f = f;
    unsigned int u = v.u;
    unsigned int r = (u + 0x7fffu + ((u >> 16) & 1u)) >> 16;
    return (unsigned short)r;
}

// ---------------------------------------------------------------------------
// Pass 0: convert x fp32 -> bf16 [M][K] in ws.
// ---------------------------------------------------------------------------
__global__ void convert_x_kernel(const float* __restrict__ x,
                                 unsigned short* __restrict__ xb) {
    const size_t i = ((size_t)blockIdx.x * 256 + threadIdx.x) * 8;
    f32x4 a = *(const f32x4*)(x + i);
    f32x4 b = *(const f32x4*)(x + i + 4);
    u16x8 v;
#pragma unroll
    for (int e = 0; e < 4; ++e) {
        v[e]     = f2bf(a[e]);
        v[e + 4] = f2bf(b[e]);
    }
    *(u16x8*)(xb + i) = v;
}

// ---------------------------------------------------------------------------
// Pass 1: dequantize packed int4 weights -> W^T bf16 [OUT_F][IN_F] in ws.
// ---------------------------------------------------------------------------
__global__ void dequant_w_kernel(const int* __restrict__ qw,
                                 const float* __restrict__ scales,
                                 const float* __restrict__ zeros,
                                 unsigned short* __restrict__ wt) {
    const int n  = blockIdx.x * 256 + threadIdx.x;
    const int k0 = blockIdx.y * 32;
    const int g  = k0 >> 7;
    const float s = scales[(size_t)g * OUT_F + n];
    const float z = zeros[(size_t)g * OUT_F + n];

    unsigned short outv[32];
#pragma unroll
    for (int i = 0; i < 16; ++i) {
        int q = qw[(size_t)(k0 / 2 + i) * OUT_F + n];
        float lo = (float)((q & 15) - 8) * s + z;        // even k = low nibble
        float hi = (float)(((q >> 4) & 15) - 8) * s + z; // odd k  = high nibble
        outv[2 * i]     = f2bf(lo);
        outv[2 * i + 1] = f2bf(hi);
    }
    u16x8* dst = (u16x8*)(wt + (size_t)n * IN_F + k0);
    const u16x8* src = (const u16x8*)outv;
#pragma unroll
    for (int i = 0; i < 4; ++i) dst[i] = src[i];
}

// ---------------------------------------------------------------------------
// Pass 2: 256x256 bf16 GEMM with mfma_f32_32x32x16_bf16.
// Round-7: identical zoned schedule to round 6 (4 fenced barriers/tile,
// counted vmcnt(6), setprio, XCD swizzle, fragment-order LDS), but MFMA shape
// 32x32x16: 32 MFMA/tile/wave (was 64) -> half issue slots / acc touches.
// Subtile = 32 rows x 16 k bf16 = 1024 B, lane l's 16 B frag at +l*16
// (A/B operand layout: row/col = lane&31, k = (lane>>5)*8 + j).
// Per-wave out 128x64 = 4 m-frags x 2 n-frags of 32x32, acc f32x16 each.
// Zones per tile t (buf p):
//  Z0 = [QUAD11(prev); READ_A0->afH0 (8), READ_BLO->bfE (4); STG SA1(t+1)->!p]
//  Z1 = [QUAD00; READ_BHI->bfO (4); STG SB_G0(t+2)->p]
//  Z2 = [QUAD01; READ_A1->afH1 (8); STG SB_G1(t+2)->p]
//  Z3 = [QUAD10; STG SA0(t+2)->p; vmcnt(6)]
// WAR: SB_G0 (even cf) last read Z0 (1 bar); SB_G1 (odd cf) last read Z1;
// SA0 (rf0-3) last read Z2 (wr0's afH1 = rf2,3); SA1->!p last read t-1.Z2.
// RAW: vmcnt(6) at Z3 retires 8 oldest of 14 in-flight = all of tile t+1.
// ---------------------------------------------------------------------------
__global__ __launch_bounds__(512, 1)
void gemm_8phase(const unsigned short* __restrict__ xb,   // [M][K] bf16
                 const unsigned short* __restrict__ wt,   // [N][K] bf16
                 const float* __restrict__ bias,
                 float* __restrict__ out) {
    constexpr int NT = IN_F / 64;  // 64 K-tiles
    __shared__ __attribute__((aligned(128))) unsigned short lds[65536]; // 128 KiB

    constexpr int NB_N = OUT_F / 256;             // 43
    constexpr int NWG  = (M_TOTAL / 256) * NB_N;  // 1376 (divisible by 8)
    constexpr int CPX  = NWG / 8;                 // 172
    const int wg = ((int)blockIdx.x % 8) * CPX + (int)blockIdx.x / 8;
    const int m0 = (wg / NB_N) * 256;
    const int n0 = (wg % NB_N) * 256;

    const int tid  = threadIdx.x;
    const int lane = tid & 63;
    const int wave = tid >> 6;       // 0..7
    const int wr = wave >> 2;        // 0..1  (M)
    const int wc = wave & 3;         // 0..3  (N)
    const int r32 = lane & 31;       // operand row/col within 32
    const int q2  = lane >> 5;       // k-half selector

    const ASG char* xbc = (const ASG char*)xb;
    const ASG char* wtc = (const ASG char*)wt;
    ASL char* ldsc = (ASL char*)lds;

    // ---- staging streams (per-thread 32-bit global byte offsets, +128 B per
    // use; wave-uniform LDS dest byte offsets).
    // A stream H (wr-half), inst i: s' = i*8+wave in 0..15 -> rf = H*4+(s'>>2),
    // kc = s'&3. Subtile byte addr = (H*16+s')*1024; lane l at +l*16.
    // B stream G (cf-parity), inst i: s'' = i*8+wave -> cf = (s''>>2)*2+G,
    // kc = s''&3. Subtile = 32768 + (cf*4+kc)*1024.
    unsigned int oA[4], oB[4];
    int dA[4], dB[4];
#pragma unroll
    for (int H = 0; H < 2; ++H)
#pragma unroll
        for (int i = 0; i < 2; ++i) {
            const int s = i * 8 + wave;
            const int rf = H * 4 + (s >> 2), kc = s & 3;
            oA[H * 2 + i] = (unsigned int)(((m0 + rf * 32 + r32) * IN_F +
                                            kc * 16 + q2 * 8) * 2);
            dA[H * 2 + i] = (H * 16 + s) * 1024;
        }
#pragma unroll
    for (int G = 0; G < 2; ++G)
#pragma unroll
        for (int i = 0; i < 2; ++i) {
            const int s = i * 8 + wave;
            const int cf = (s >> 2) * 2 + G, kc = s & 3;
            oB[G * 2 + i] = (unsigned int)(((n0 + cf * 32 + r32) * IN_F +
                                            kc * 16 + q2 * 8) * 2);
            dB[G * 2 + i] = 32768 + (cf * 4 + kc) * 1024;
        }

#define STG_A(H, P)                                                            \
    do {                                                                       \
        _Pragma("unroll") for (int _i = 0; _i < 2; ++_i)                       \
            __builtin_amdgcn_global_load_lds(                                  \
                (ASG const unsigned int*)(xbc + oA[(H) * 2 + _i]),             \
                (ASL unsigned int*)(ldsc + dA[(H) * 2 + _i] + (P) * 65536),    \
                16, 0, 0);                                                     \
    } while (0)
#define STG_BG(G, P)                                                           \
    do {                                                                       \
        _Pragma("unroll") for (int _i = 0; _i < 2; ++_i)                       \
            __builtin_amdgcn_global_load_lds(                                  \
                (ASG const unsigned int*)(wtc + oB[(G) * 2 + _i]),             \
                (ASL unsigned int*)(ldsc + dB[(G) * 2 + _i] + (P) * 65536),    \
                16, 0, 0);                                                     \
    } while (0)
#define ADV_A(H) do { oA[(H)*2] += 128; oA[(H)*2+1] += 128; } while (0)
#define ADV_BG(G) do { oB[(G)*2] += 128; oB[(G)*2+1] += 128; } while (0)

#define BAR()                                                                  \
    do {                                                                       \
        __builtin_amdgcn_sched_barrier(0);                                     \
        __builtin_amdgcn_s_barrier();                                          \
        __builtin_amdgcn_sched_barrier(0);                                     \
    } while (0)

    // fragment registers: afH = 2 m-frags x 4 kc; bfE/bfO = 1 cf x 4 kc
    bf16x8 afH0[2][4], afH1[2][4];
    bf16x8 bfE[4], bfO[4];
    f32x16 acc[4][2];   // 4 m-frags x 2 n-frags of 32x32
#pragma unroll
    for (int i = 0; i < 4; ++i)
#pragma unroll
        for (int j = 0; j < 2; ++j) acc[i][j] = (f32x16)0.0f;

    // LDS read bases in short units: subtile (rf*4+kc) at *512 shorts.
#define READ_A0(P)                                                             \
    do {                                                                       \
        const unsigned short* _ab = lds + (P) * 32768 + lane * 8;              \
        _Pragma("unroll") for (int _m = 0; _m < 2; ++_m)                       \
        _Pragma("unroll") for (int _kc = 0; _kc < 4; ++_kc)                    \
            afH0[_m][_kc] = *(const bf16x8*)(_ab +                             \
                (((wr * 4 + _m) * 4 + _kc) << 9));                             \
    } while (0)
#define READ_A1(P)                                                             \
    do {                                                                       \
        const unsigned short* _ab = lds + (P) * 32768 + lane * 8;              \
        _Pragma("unroll") for (int _m = 0; _m < 2; ++_m)                       \
        _Pragma("unroll") for (int _kc = 0; _kc < 4; ++_kc)                    \
            afH1[_m][_kc] = *(const bf16x8*)(_ab +                             \
                (((wr * 4 + 2 + _m) * 4 + _kc) << 9));                         \
    } while (0)
#define READ_BLO(P)                                                            \
    do {                                                                       \
        const unsigned short* _bb = lds + (P) * 32768 + 16384 + lane * 8;      \
        _Pragma("unroll") for (int _kc = 0; _kc < 4; ++_kc)                    \
            bfE[_kc] = *(const bf16x8*)(_bb +                                  \
                (((wc * 2) * 4 + _kc) << 9));                                  \
    } while (0)
#define READ_BHI(P)                                                            \
    do {                                                                       \
        const unsigned short* _bb = lds + (P) * 32768 + 16384 + lane * 8;      \
        _Pragma("unroll") for (int _kc = 0; _kc < 4; ++_kc)                    \
            bfO[_kc] = *(const bf16x8*)(_bb +                                  \
                (((wc * 2 + 1) * 4 + _kc) << 9));                              \
    } while (0)

    // QUAD(MH,NH): m-frags {MH*2, MH*2+1} x 1 n-frag x 4 kc = 8 MFMA 32x32x16
#define QUADX(AF, BF, MH, NH)                                                  \
    do {                                                                       \
        __builtin_amdgcn_s_setprio(1);                                         \
        _Pragma("unroll") for (int _m = 0; _m < 2; ++_m)                       \
        _Pragma("unroll") for (int _kc = 0; _kc < 4; ++_kc)                    \
            acc[(MH) * 2 + _m][(NH)] =                                         \
                __builtin_amdgcn_mfma_f32_32x32x16_bf16(                       \
                    AF[_m][_kc], BF[_kc], acc[(MH) * 2 + _m][(NH)], 0, 0, 0);  \
        __builtin_amdgcn_s_setprio(0);                                         \
    } while (0)

    // ---- prologue: tile0 {BG0,BG1,A0,A1}, tile1 {BG0,BG1,A0}; 6 in flight.
    STG_BG(0, 0); ADV_BG(0);
    STG_BG(1, 0); ADV_BG(1);
    STG_A(0, 0);  ADV_A(0);
    STG_A(1, 0);  ADV_A(1);    // A1 stream -> T=1
    STG_BG(0, 1); ADV_BG(0);   // -> T=2
    STG_BG(1, 1); ADV_BG(1);   // -> T=2
    STG_A(0, 1);  ADV_A(0);    // -> T=2
    __builtin_amdgcn_sched_barrier(0);
    asm volatile("s_waitcnt vmcnt(6)" ::: "memory");  // tile0 resident
    BAR();

#pragma unroll 1
    for (int tt = 0; tt < NT; tt += 2) {
        const bool g2 = (tt + 2 < NT);
        const bool g3 = (tt + 3 < NT);
        // ================= tile tt (buf 0) =================
        // Z0 (continues prev iter's QUAD11)
        READ_A0(0);
        READ_BLO(0);
        STG_A(1, 1); ADV_A(1);                // A1(tt+1) -> buf1
        BAR();
        // Z1
        QUADX(afH0, bfE, 0, 0);
        READ_BHI(0);
        if (g2) STG_BG(0, 0);
        ADV_BG(0);                            // B-G0(tt+2) -> buf0
        BAR();
        // Z2
        QUADX(afH0, bfO, 0, 1);
        READ_A1(0);
        if (g2) STG_BG(1, 0);
        ADV_BG(1);                            // B-G1(tt+2) -> buf0
        BAR();
        // Z3
        QUADX(afH1, bfE, 1, 0);
        if (g2) STG_A(0, 0);
        ADV_A(0);                             // A0(tt+2) -> buf0
        __builtin_amdgcn_sched_barrier(0);
        if (tt < NT - 2) {
            asm volatile("s_waitcnt vmcnt(6)" ::: "memory");
        } else {
            asm volatile("s_waitcnt vmcnt(0)" ::: "memory");
        }
        BAR();
        QUADX(afH1, bfO, 1, 1);
        // ================= tile tt+1 (buf 1) =================
        // Z0
        READ_A0(1);
        READ_BLO(1);
        if (g2) STG_A(1, 0);
        ADV_A(1);                             // A1(tt+2) -> buf0
        BAR();
        // Z1
        QUADX(afH0, bfE, 0, 0);
        READ_BHI(1);
        if (g3) STG_BG(0, 1);
        ADV_BG(0);                            // B-G0(tt+3) -> buf1
        BAR();
        // Z2
        QUADX(afH0, bfO, 0, 1);
        READ_A1(1);
        if (g3) STG_BG(1, 1);
        ADV_BG(1);                            // B-G1(tt+3) -> buf1
        BAR();
        // Z3
        QUADX(afH1, bfE, 1, 0);
        if (g3) STG_A(0, 1);
        ADV_A(0);                             // A0(tt+3) -> buf1
        __builtin_amdgcn_sched_barrier(0);
        if (tt + 1 < NT - 2) {
            asm volatile("s_waitcnt vmcnt(6)" ::: "memory");
        } else {
            asm volatile("s_waitcnt vmcnt(0)" ::: "memory");
        }
        BAR();
        QUADX(afH1, bfO, 1, 1);
    }

    // ---- epilogue: 32x32 C/D layout col = lane&31,
    //      row = (reg&3) + 8*(reg>>2) + 4*(lane>>5)   [m74/m101 verified]
#pragma unroll
    for (int nf = 0; nf < 2; ++nf) {
        const int col = n0 + wc * 64 + nf * 32 + r32;
        const float bv = bias[col];
#pragma unroll
        for (int mf = 0; mf < 4; ++mf) {
            const int row0 = m0 + wr * 128 + mf * 32 + q2 * 4;
#pragma unroll
            for (int r = 0; r < 16; ++r) {
                const int row = row0 + (r & 3) + ((r >> 2) << 3);
                out[(size_t)row * OUT_F + col] = acc[mf][nf][r] + bv;
            }
        }
    }
#undef STG_A
#undef STG_BG
#undef ADV_A
#undef ADV_BG
#undef BAR
#undef READ_A0
#undef READ_A1
#undef READ_BLO
#undef READ_BHI
#undef QUADX
}

// ---------------------------------------------------------------------------
// Fallback GEMM (reg-staged 128x128), for small ws.
// ---------------------------------------------------------------------------
template <bool PREW>
__global__ __launch_bounds__(256, 2)
void gemm_kernel(const float* __restrict__ x,
                 const unsigned short* __restrict__ wt,
                 const int* __restrict__ qw,
                 const float* __restrict__ scales,
                 const float* __restrict__ zeros,
                 const float* __restrict__ bias,
                 float* __restrict__ out) {
    constexpr int BM = 128, BN = 128, BK = 64;
    constexpr int LDK = BK + 8;
    constexpr int NT = IN_F / BK;

    __shared__ unsigned short As[BM * LDK];
    __shared__ unsigned short Bs[BN * LDK];

    const int bid = blockIdx.x;
    constexpr int NB_N = OUT_F / BN;
    const int m0 = (bid / NB_N) * BM;
    const int n0 = (bid % NB_N) * BN;

    const int tid  = threadIdx.x;
    const int lane = tid & 63;
    const int wave = tid >> 6;
    const int wr = wave >> 1, wc = wave & 1;

    const int st_row = tid >> 3;
    const int st_col = (tid & 7) * 8;

    f32x4 areg[4][2];
    u32x4 breg[4];
    int   qreg[16];
    float s_, z_;
    const int b_n  = tid & 127;
    const int b_kp = (tid >> 7) * 16;

    auto load_tile = [&](int kt) {
        {
            const float* base = x + (size_t)m0 * IN_F + (size_t)kt * BK + st_col;
#pragma unroll
            for (int p = 0; p < 4; ++p) {
                const float* rp = base + (size_t)(p * 32 + st_row) * IN_F;
                areg[p][0] = *(const f32x4*)rp;
                areg[p][1] = *(const f32x4*)(rp + 4);
            }
        }
        if constexpr (PREW) {
            const unsigned short* base = wt + (size_t)n0 * IN_F + (size_t)kt * BK + st_col;
#pragma unroll
            for (int p = 0; p < 4; ++p)
                breg[p] = *(const u32x4*)(base + (size_t)(p * 32 + st_row) * IN_F);
        } else {
            const int kp0 = kt * (BK / 2) + b_kp;
#pragma unroll
            for (int i = 0; i < 16; ++i)
                qreg[i] = qw[(size_t)(kp0 + i) * OUT_F + n0 + b_n];
            const int g = (kt * BK) >> 7;
            s_ = scales[(size_t)g * OUT_F + n0 + b_n];
            z_ = zeros[(size_t)g * OUT_F + n0 + b_n];
        }
    };

    auto write_lds = [&]() {
#pragma unroll
        for (int p = 0; p < 4; ++p) {
            u16x8 v;
#pragma unroll
            for (int e = 0; e < 4; ++e) {
                v[e]     = f2bf(areg[p][0][e]);
                v[e + 4] = f2bf(areg[p][1][e]);
            }
            *(u16x8*)(&As[(p * 32 + st_row) * LDK + st_col]) = v;
        }
        if constexpr (PREW) {
#pragma unroll
            for (int p = 0; p < 4; ++p)
                *(u32x4*)(&Bs[(p * 32 + st_row) * LDK + st_col]) = breg[p];
        } else {
            unsigned short tmp[32];
#pragma unroll
            for (int i = 0; i < 16; ++i) {
                int q = qreg[i];
                tmp[2 * i]     = f2bf((float)((q & 15) - 8) * s_ + z_);
                tmp[2 * i + 1] = f2bf((float)(((q >> 4) & 15) - 8) * s_ + z_);
            }
            const u16x8* srcv = (const u16x8*)tmp;
#pragma unroll
            for (int i = 0; i < 4; ++i)
                *(u16x8*)(&Bs[b_n * LDK + 2 * b_kp + 8 * i]) = srcv[i];
        }
    };

    f32x4 acc[4][4];
#pragma unroll
    for (int i = 0; i < 4; ++i)
#pragma unroll
        for (int j = 0; j < 4; ++j) acc[i][j] = (f32x4)0.0f;

    load_tile(0);

#pragma unroll 1
    for (int kt = 0; kt < NT; ++kt) {
        __syncthreads();
        write_lds();
        __syncthreads();
        if (kt + 1 < NT) load_tile(kt + 1);

#pragma unroll
        for (int kk = 0; kk < 2; ++kk) {
            const int kidx = kk * 32 + ((lane >> 4) << 3);
            bf16x8 afv[4], bfv[4];
#pragma unroll
            for (int i = 0; i < 4; ++i)
                afv[i] = *(const bf16x8*)(&As[(wr * 64 + i * 16 + (lane & 15)) * LDK + kidx]);
#pragma unroll
            for (int j = 0; j < 4; ++j)
                bfv[j] = *(const bf16x8*)(&Bs[(wc * 64 + j * 16 + (lane & 15)) * LDK + kidx]);
#pragma unroll
            for (int i = 0; i < 4; ++i)
#pragma unroll
                for (int j = 0; j < 4; ++j)
                    acc[i][j] = __builtin_amdgcn_mfma_f32_16x16x32_bf16(afv[i], bfv[j], acc[i][j], 0, 0, 0);
        }
    }

    const int orow_base = m0 + wr * 64 + ((lane >> 4) << 2);
    const int ocol_base = n0 + wc * 64 + (lane & 15);
#pragma unroll
    for (int j = 0; j < 4; ++j) {
        const float bv = bias[ocol_base + j * 16];
#pragma unroll
        for (int i = 0; i < 4; ++i) {
#pragma unroll
            for (int q = 0; q < 4; ++q) {
                out[(size_t)(orow_base + i * 16 + q) * OUT_F + (ocol_base + j * 16)] =
                    acc[i][j][q] + bv;
            }
        }
    }
}

// ---------------------------------------------------------------------------
extern "C" void kernel_launch(void* const* d_in, const int* in_sizes, int n_in,
                              void* d_out, int out_size, void* d_ws, size_t ws_size,
                              hipStream_t stream) {
    const float* x      = (const float*)d_in[0];
    const int*   qw     = (const int*)d_in[1];
    const float* scales = (const float*)d_in[2];
    const float* zeros  = (const float*)d_in[3];
    const float* bias   = (const float*)d_in[4];
    float* out = (float*)d_out;

    const size_t wt_bytes = (size_t)OUT_F * IN_F * sizeof(unsigned short);   // 90.2 MB
    const size_t xb_bytes = (size_t)M_TOTAL * IN_F * sizeof(unsigned short); // 67.1 MB

    if (ws_size >= wt_bytes + xb_bytes) {
        unsigned short* wt = (unsigned short*)d_ws;
        unsigned short* xb = (unsigned short*)((char*)d_ws + wt_bytes);
        convert_x_kernel<<<(M_TOTAL * IN_F) / (256 * 8), 256, 0, stream>>>(x, xb);
        dequant_w_kernel<<<dim3(OUT_F / 256, IN_F / 32), 256, 0, stream>>>(qw, scales, zeros, wt);
        gemm_8phase<<<(M_TOTAL / 256) * (OUT_F / 256), 512, 0, stream>>>(xb, wt, bias, out);
    } else if (ws_size >= wt_bytes) {
        unsigned short* wt = (unsigned short*)d_ws;
        dequant_w_kernel<<<dim3(OUT_F / 256, IN_F / 32), 256, 0, stream>>>(qw, scales, zeros, wt);
        gemm_kernel<true><<<(M_TOTAL / 128) * (OUT_F / 128), 256, 0, stream>>>(x, wt, qw, scales, zeros, bias, out);
    } else {
        gemm_kernel<false><<<(M_TOTAL / 128) * (OUT_F / 128), 256, 0, stream>>>(x, nullptr, qw, scales, zeros, bias, out);
    }
}

// Round 8
// 725.940 us; speedup vs baseline: 1.2223x; 1.2223x over previous
//
#include <hip/hip_runtime.h>
#include <hip/hip_bf16.h>

#define IN_F 4096
#define OUT_F 11008
#define GSIZE 128
#define M_TOTAL 8192

typedef float f32x4 __attribute__((ext_vector_type(4)));
typedef float f32x16 __attribute__((ext_vector_type(16)));
typedef unsigned short u16x8 __attribute__((ext_vector_type(8)));
typedef unsigned int u32x4 __attribute__((ext_vector_type(4)));
typedef __bf16 bf16x8 __attribute__((ext_vector_type(8)));

#define ASG __attribute__((address_space(1)))
#define ASL __attribute__((address_space(3)))

__device__ __forceinline__ unsigned short f2bf(float f) {
    union { float f; unsigned int u; } v;
    v.f = f;
    unsigned int u = v.u;
    unsigned int r = (u + 0x7fffu + ((u >> 16) & 1u)) >> 16;
    return (unsigned short)r;
}

// ---------------------------------------------------------------------------
// Fragment-subtile global layout (matches MFMA 32x32x16 operand order):
//   subtile (f, kf) = 32 rows x 16 k, 1024 B at ((f * (K/16) + kf) * 1024).
//   lane l = (q2*32 + r): holds elem[row = f*32 + r][k = kf*16 + q2*8 .. +8].
// A staging instruction reads lane*16 -> 1024 CONTIGUOUS bytes (coalesced),
// writes linear LDS; ds_read fragment layout unchanged.
// ---------------------------------------------------------------------------

// Pass 0: x fp32 [M][K] -> xb fragment order [M/32][K/16][64][8].
// grid (M/32, 8), block 256. Reads coalesced (row-contiguous 32B/thread).
__global__ void convert_x_frag_kernel(const float* __restrict__ x,
                                      unsigned short* __restrict__ xb) {
    const int mf = blockIdx.x;            // 0..255
    const int r  = threadIdx.x >> 3;      // 0..31
    const int kb = (threadIdx.x & 7) * 8; // 0..56
    const int k0 = blockIdx.y * 512;
    const float* src = x + (size_t)(mf * 32 + r) * IN_F;
    unsigned short* dst = xb + (size_t)mf * (IN_F / 16) * 512;
#pragma unroll
    for (int kk = 0; kk < 512; kk += 64) {
        const int k = k0 + kk + kb;
        f32x4 a = *(const f32x4*)(src + k);
        f32x4 b = *(const f32x4*)(src + k + 4);
        u16x8 v;
#pragma unroll
        for (int e = 0; e < 4; ++e) {
            v[e]     = f2bf(a[e]);
            v[e + 4] = f2bf(b[e]);
        }
        const int kf = k >> 4, q2 = (k >> 3) & 1;
        *(u16x8*)(dst + (size_t)kf * 512 + (q2 * 32 + r) * 8) = v;
    }
}

// Pass 1: int4 weights -> wt fragment order [N/32][K/16][64][8].
// grid (43, 128), block 256. qweight reads coalesced across n.
__global__ void dequant_w_frag_kernel(const int* __restrict__ qw,
                                      const float* __restrict__ scales,
                                      const float* __restrict__ zeros,
                                      unsigned short* __restrict__ wt) {
    const int n  = blockIdx.x * 256 + threadIdx.x;   // 0..11007
    const int k0 = blockIdx.y * 32;
    const int g  = k0 >> 7;
    const float s = scales[(size_t)g * OUT_F + n];
    const float z = zeros[(size_t)g * OUT_F + n];

    unsigned short outv[32];
#pragma unroll
    for (int i = 0; i < 16; ++i) {
        int q = qw[(size_t)(k0 / 2 + i) * OUT_F + n];
        float lo = (float)((q & 15) - 8) * s + z;        // even k = low nibble
        float hi = (float)(((q >> 4) & 15) - 8) * s + z; // odd k  = high nibble
        outv[2 * i]     = f2bf(lo);
        outv[2 * i + 1] = f2bf(hi);
    }
    const int nf = n >> 5, r32 = n & 31;
    unsigned short* base = wt + (size_t)nf * (IN_F / 16) * 512 +
                           (size_t)(k0 >> 4) * 512;
    const u16x8* sv = (const u16x8*)outv;
#pragma unroll
    for (int c = 0; c < 4; ++c)   // chunk c: k = k0 + c*8 .. +8
        *(u16x8*)(base + (c >> 1) * 512 + ((c & 1) * 32 + r32) * 8) = sv[c];
}

// Pass 1b (fallback path): row-major W^T bf16 [OUT_F][IN_F].
__global__ void dequant_w_rowmajor_kernel(const int* __restrict__ qw,
                                          const float* __restrict__ scales,
                                          const float* __restrict__ zeros,
                                          unsigned short* __restrict__ wt) {
    const int n  = blockIdx.x * 256 + threadIdx.x;
    const int k0 = blockIdx.y * 32;
    const int g  = k0 >> 7;
    const float s = scales[(size_t)g * OUT_F + n];
    const float z = zeros[(size_t)g * OUT_F + n];

    unsigned short outv[32];
#pragma unroll
    for (int i = 0; i < 16; ++i) {
        int q = qw[(size_t)(k0 / 2 + i) * OUT_F + n];
        float lo = (float)((q & 15) - 8) * s + z;
        float hi = (float)(((q >> 4) & 15) - 8) * s + z;
        outv[2 * i]     = f2bf(lo);
        outv[2 * i + 1] = f2bf(hi);
    }
    u16x8* dst = (u16x8*)(wt + (size_t)n * IN_F + k0);
    const u16x8* src = (const u16x8*)outv;
#pragma unroll
    for (int i = 0; i < 4; ++i) dst[i] = src[i];
}

// ---------------------------------------------------------------------------
// Pass 2: 256x256 bf16 GEMM, mfma_f32_32x32x16, round-7 zoned schedule,
// with COALESCED staging from fragment-order global operands.
// Zones per tile t (buf p), 4 fenced barriers:
//  Z0 = [QUAD11(prev); READ_A0->afH0, READ_BLO->bfE; STG A1(t+1)->!p]
//  Z1 = [QUAD00; READ_BHI->bfO; STG B-G0(t+2)->p]
//  Z2 = [QUAD01; READ_A1->afH1; STG B-G1(t+2)->p]
//  Z3 = [QUAD10; STG A0(t+2)->p; vmcnt(6)]
// WAR/RAW identical to round 7 (passing). Each stage inst now reads a
// contiguous 1024-B global burst (oX + lane*16).
// ---------------------------------------------------------------------------
__global__ __launch_bounds__(512, 1)
void gemm_8phase(const unsigned short* __restrict__ xb,   // frag order
                 const unsigned short* __restrict__ wt,   // frag order
                 const float* __restrict__ bias,
                 float* __restrict__ out) {
    constexpr int NT = IN_F / 64;  // 64 K-tiles
    constexpr int NKF = IN_F / 16; // 256 k-frags
    __shared__ __attribute__((aligned(128))) unsigned short lds[65536]; // 128 KiB

    constexpr int NB_N = OUT_F / 256;             // 43
    constexpr int NWG  = (M_TOTAL / 256) * NB_N;  // 1376 (divisible by 8)
    constexpr int CPX  = NWG / 8;                 // 172
    const int wg = ((int)blockIdx.x % 8) * CPX + (int)blockIdx.x / 8;
    const int m0 = (wg / NB_N) * 256;
    const int n0 = (wg % NB_N) * 256;

    const int tid  = threadIdx.x;
    const int lane = tid & 63;
    const int wave = tid >> 6;       // 0..7
    const int wr = wave >> 2;        // 0..1  (M)
    const int wc = wave & 3;         // 0..3  (N)
    const int r32 = lane & 31;
    const int q2  = lane >> 5;

    const ASG char* xbc = (const ASG char*)xb;
    const ASG char* wtc = (const ASG char*)wt;
    ASL char* ldsc = (ASL char*)lds;

    // ---- staging streams: per-thread 32-bit global byte offsets into the
    // fragment-order arrays (+4096 B per tile), wave-uniform LDS dests.
    const int mfb = m0 >> 5;   // base m-frag
    const int nfb = n0 >> 5;   // base n-frag
    unsigned int oA[4], oB[4];
    int dA[4], dB[4];
#pragma unroll
    for (int H = 0; H < 2; ++H)
#pragma unroll
        for (int i = 0; i < 2; ++i) {
            const int s = i * 8 + wave;
            const int rf = s >> 2, kc = s & 3;
            oA[H * 2 + i] = (unsigned int)(((mfb + H * 4 + rf) * NKF + kc) * 1024 +
                                           lane * 16);
            dA[H * 2 + i] = (H * 16 + s) * 1024;
        }
#pragma unroll
    for (int G = 0; G < 2; ++G)
#pragma unroll
        for (int i = 0; i < 2; ++i) {
            const int s = i * 8 + wave;
            const int cf = (s >> 2) * 2 + G, kc = s & 3;
            oB[G * 2 + i] = (unsigned int)(((nfb + cf) * NKF + kc) * 1024 +
                                           lane * 16);
            dB[G * 2 + i] = 32768 + (cf * 4 + kc) * 1024;
        }

#define STG_A(H, P)                                                            \
    do {                                                                       \
        _Pragma("unroll") for (int _i = 0; _i < 2; ++_i)                       \
            __builtin_amdgcn_global_load_lds(                                  \
                (ASG const unsigned int*)(xbc + oA[(H) * 2 + _i]),             \
                (ASL unsigned int*)(ldsc + dA[(H) * 2 + _i] + (P) * 65536),    \
                16, 0, 0);                                                     \
    } while (0)
#define STG_BG(G, P)                                                           \
    do {                                                                       \
        _Pragma("unroll") for (int _i = 0; _i < 2; ++_i)                       \
            __builtin_amdgcn_global_load_lds(                                  \
                (ASG const unsigned int*)(wtc + oB[(G) * 2 + _i]),             \
                (ASL unsigned int*)(ldsc + dB[(G) * 2 + _i] + (P) * 65536),    \
                16, 0, 0);                                                     \
    } while (0)
#define ADV_A(H) do { oA[(H)*2] += 4096; oA[(H)*2+1] += 4096; } while (0)
#define ADV_BG(G) do { oB[(G)*2] += 4096; oB[(G)*2+1] += 4096; } while (0)

#define BAR()                                                                  \
    do {                                                                       \
        __builtin_amdgcn_sched_barrier(0);                                     \
        __builtin_amdgcn_s_barrier();                                          \
        __builtin_amdgcn_sched_barrier(0);                                     \
    } while (0)

    bf16x8 afH0[2][4], afH1[2][4];
    bf16x8 bfE[4], bfO[4];
    f32x16 acc[4][2];
#pragma unroll
    for (int i = 0; i < 4; ++i)
#pragma unroll
        for (int j = 0; j < 2; ++j) acc[i][j] = (f32x16)0.0f;

#define READ_A0(P)                                                             \
    do {                                                                       \
        const unsigned short* _ab = lds + (P) * 32768 + lane * 8;              \
        _Pragma("unroll") for (int _m = 0; _m < 2; ++_m)                       \
        _Pragma("unroll") for (int _kc = 0; _kc < 4; ++_kc)                    \
            afH0[_m][_kc] = *(const bf16x8*)(_ab +                             \
                (((wr * 4 + _m) * 4 + _kc) << 9));                             \
    } while (0)
#define READ_A1(P)                                                             \
    do {                                                                       \
        const unsigned short* _ab = lds + (P) * 32768 + lane * 8;              \
        _Pragma("unroll") for (int _m = 0; _m < 2; ++_m)                       \
        _Pragma("unroll") for (int _kc = 0; _kc < 4; ++_kc)                    \
            afH1[_m][_kc] = *(const bf16x8*)(_ab +                             \
                (((wr * 4 + 2 + _m) * 4 + _kc) << 9));                         \
    } while (0)
#define READ_BLO(P)                                                            \
    do {                                                                       \
        const unsigned short* _bb = lds + (P) * 32768 + 16384 + lane * 8;      \
        _Pragma("unroll") for (int _kc = 0; _kc < 4; ++_kc)                    \
            bfE[_kc] = *(const bf16x8*)(_bb +                                  \
                (((wc * 2) * 4 + _kc) << 9));                                  \
    } while (0)
#define READ_BHI(P)                                                            \
    do {                                                                       \
        const unsigned short* _bb = lds + (P) * 32768 + 16384 + lane * 8;      \
        _Pragma("unroll") for (int _kc = 0; _kc < 4; ++_kc)                    \
            bfO[_kc] = *(const bf16x8*)(_bb +                                  \
                (((wc * 2 + 1) * 4 + _kc) << 9));                              \
    } while (0)

#define QUADX(AF, BF, MH, NH)                                                  \
    do {                                                                       \
        __builtin_amdgcn_s_setprio(1);                                         \
        _Pragma("unroll") for (int _m = 0; _m < 2; ++_m)                       \
        _Pragma("unroll") for (int _kc = 0; _kc < 4; ++_kc)                    \
            acc[(MH) * 2 + _m][(NH)] =                                         \
                __builtin_amdgcn_mfma_f32_32x32x16_bf16(                       \
                    AF[_m][_kc], BF[_kc], acc[(MH) * 2 + _m][(NH)], 0, 0, 0);  \
        __builtin_amdgcn_s_setprio(0);                                         \
    } while (0)

    // ---- prologue: tile0 {BG0,BG1,A0,A1}, tile1 {BG0,BG1,A0}; 6 in flight.
    STG_BG(0, 0); ADV_BG(0);
    STG_BG(1, 0); ADV_BG(1);
    STG_A(0, 0);  ADV_A(0);
    STG_A(1, 0);  ADV_A(1);    // A1 stream -> T=1
    STG_BG(0, 1); ADV_BG(0);   // -> T=2
    STG_BG(1, 1); ADV_BG(1);   // -> T=2
    STG_A(0, 1);  ADV_A(0);    // -> T=2
    __builtin_amdgcn_sched_barrier(0);
    asm volatile("s_waitcnt vmcnt(6)" ::: "memory");  // tile0 resident
    BAR();

#pragma unroll 1
    for (int tt = 0; tt < NT; tt += 2) {
        const bool g2 = (tt + 2 < NT);
        const bool g3 = (tt + 3 < NT);
        // ================= tile tt (buf 0) =================
        // Z0
        READ_A0(0);
        READ_BLO(0);
        STG_A(1, 1); ADV_A(1);                // A1(tt+1) -> buf1
        BAR();
        // Z1
        QUADX(afH0, bfE, 0, 0);
        READ_BHI(0);
        if (g2) STG_BG(0, 0);
        ADV_BG(0);                            // B-G0(tt+2) -> buf0
        BAR();
        // Z2
        QUADX(afH0, bfO, 0, 1);
        READ_A1(0);
        if (g2) STG_BG(1, 0);
        ADV_BG(1);                            // B-G1(tt+2) -> buf0
        BAR();
        // Z3
        QUADX(afH1, bfE, 1, 0);
        if (g2) STG_A(0, 0);
        ADV_A(0);                             // A0(tt+2) -> buf0
        __builtin_amdgcn_sched_barrier(0);
        if (tt < NT - 2) {
            asm volatile("s_waitcnt vmcnt(6)" ::: "memory");
        } else {
            asm volatile("s_waitcnt vmcnt(0)" ::: "memory");
        }
        BAR();
        QUADX(afH1, bfO, 1, 1);
        // ================= tile tt+1 (buf 1) =================
        // Z0
        READ_A0(1);
        READ_BLO(1);
        if (g2) STG_A(1, 0);
        ADV_A(1);                             // A1(tt+2) -> buf0
        BAR();
        // Z1
        QUADX(afH0, bfE, 0, 0);
        READ_BHI(1);
        if (g3) STG_BG(0, 1);
        ADV_BG(0);                            // B-G0(tt+3) -> buf1
        BAR();
        // Z2
        QUADX(afH0, bfO, 0, 1);
        READ_A1(1);
        if (g3) STG_BG(1, 1);
        ADV_BG(1);                            // B-G1(tt+3) -> buf1
        BAR();
        // Z3
        QUADX(afH1, bfE, 1, 0);
        if (g3) STG_A(0, 1);
        ADV_A(0);                             // A0(tt+3) -> buf1
        __builtin_amdgcn_sched_barrier(0);
        if (tt + 1 < NT - 2) {
            asm volatile("s_waitcnt vmcnt(6)" ::: "memory");
        } else {
            asm volatile("s_waitcnt vmcnt(0)" ::: "memory");
        }
        BAR();
        QUADX(afH1, bfO, 1, 1);
    }

    // ---- epilogue: 32x32 C/D layout col = lane&31,
    //      row = (reg&3) + 8*(reg>>2) + 4*(lane>>5)
#pragma unroll
    for (int nf = 0; nf < 2; ++nf) {
        const int col = n0 + wc * 64 + nf * 32 + r32;
        const float bv = bias[col];
#pragma unroll
        for (int mf = 0; mf < 4; ++mf) {
            const int row0 = m0 + wr * 128 + mf * 32 + q2 * 4;
#pragma unroll
            for (int r = 0; r < 16; ++r) {
                const int row = row0 + (r & 3) + ((r >> 2) << 3);
                out[(size_t)row * OUT_F + col] = acc[mf][nf][r] + bv;
            }
        }
    }
#undef STG_A
#undef STG_BG
#undef ADV_A
#undef ADV_BG
#undef BAR
#undef READ_A0
#undef READ_A1
#undef READ_BLO
#undef READ_BHI
#undef QUADX
}

// ---------------------------------------------------------------------------
// Fallback GEMM (reg-staged 128x128, row-major operands), for small ws.
// ---------------------------------------------------------------------------
template <bool PREW>
__global__ __launch_bounds__(256, 2)
void gemm_kernel(const float* __restrict__ x,
                 const unsigned short* __restrict__ wt,
                 const int* __restrict__ qw,
                 const float* __restrict__ scales,
                 const float* __restrict__ zeros,
                 const float* __restrict__ bias,
                 float* __restrict__ out) {
    constexpr int BM = 128, BN = 128, BK = 64;
    constexpr int LDK = BK + 8;
    constexpr int NT = IN_F / BK;

    __shared__ unsigned short As[BM * LDK];
    __shared__ unsigned short Bs[BN * LDK];

    const int bid = blockIdx.x;
    constexpr int NB_N = OUT_F / BN;
    const int m0 = (bid / NB_N) * BM;
    const int n0 = (bid % NB_N) * BN;

    const int tid  = threadIdx.x;
    const int lane = tid & 63;
    const int wave = tid >> 6;
    const int wr = wave >> 1, wc = wave & 1;

    const int st_row = tid >> 3;
    const int st_col = (tid & 7) * 8;

    f32x4 areg[4][2];
    u32x4 breg[4];
    int   qreg[16];
    float s_, z_;
    const int b_n  = tid & 127;
    const int b_kp = (tid >> 7) * 16;

    auto load_tile = [&](int kt) {
        {
            const float* base = x + (size_t)m0 * IN_F + (size_t)kt * BK + st_col;
#pragma unroll
            for (int p = 0; p < 4; ++p) {
                const float* rp = base + (size_t)(p * 32 + st_row) * IN_F;
                areg[p][0] = *(const f32x4*)rp;
                areg[p][1] = *(const f32x4*)(rp + 4);
            }
        }
        if constexpr (PREW) {
            const unsigned short* base = wt + (size_t)n0 * IN_F + (size_t)kt * BK + st_col;
#pragma unroll
            for (int p = 0; p < 4; ++p)
                breg[p] = *(const u32x4*)(base + (size_t)(p * 32 + st_row) * IN_F);
        } else {
            const int kp0 = kt * (BK / 2) + b_kp;
#pragma unroll
            for (int i = 0; i < 16; ++i)
                qreg[i] = qw[(size_t)(kp0 + i) * OUT_F + n0 + b_n];
            const int g = (kt * BK) >> 7;
            s_ = scales[(size_t)g * OUT_F + n0 + b_n];
            z_ = zeros[(size_t)g * OUT_F + n0 + b_n];
        }
    };

    auto write_lds = [&]() {
#pragma unroll
        for (int p = 0; p < 4; ++p) {
            u16x8 v;
#pragma unroll
            for (int e = 0; e < 4; ++e) {
                v[e]     = f2bf(areg[p][0][e]);
                v[e + 4] = f2bf(areg[p][1][e]);
            }
            *(u16x8*)(&As[(p * 32 + st_row) * LDK + st_col]) = v;
        }
        if constexpr (PREW) {
#pragma unroll
            for (int p = 0; p < 4; ++p)
                *(u32x4*)(&Bs[(p * 32 + st_row) * LDK + st_col]) = breg[p];
        } else {
            unsigned short tmp[32];
#pragma unroll
            for (int i = 0; i < 16; ++i) {
                int q = qreg[i];
                tmp[2 * i]     = f2bf((float)((q & 15) - 8) * s_ + z_);
                tmp[2 * i + 1] = f2bf((float)(((q >> 4) & 15) - 8) * s_ + z_);
            }
            const u16x8* srcv = (const u16x8*)tmp;
#pragma unroll
            for (int i = 0; i < 4; ++i)
                *(u16x8*)(&Bs[b_n * LDK + 2 * b_kp + 8 * i]) = srcv[i];
        }
    };

    f32x4 acc[4][4];
#pragma unroll
    for (int i = 0; i < 4; ++i)
#pragma unroll
        for (int j = 0; j < 4; ++j) acc[i][j] = (f32x4)0.0f;

    load_tile(0);

#pragma unroll 1
    for (int kt = 0; kt < NT; ++kt) {
        __syncthreads();
        write_lds();
        __syncthreads();
        if (kt + 1 < NT) load_tile(kt + 1);

#pragma unroll
        for (int kk = 0; kk < 2; ++kk) {
            const int kidx = kk * 32 + ((lane >> 4) << 3);
            bf16x8 afv[4], bfv[4];
#pragma unroll
            for (int i = 0; i < 4; ++i)
                afv[i] = *(const bf16x8*)(&As[(wr * 64 + i * 16 + (lane & 15)) * LDK + kidx]);
#pragma unroll
            for (int j = 0; j < 4; ++j)
                bfv[j] = *(const bf16x8*)(&Bs[(wc * 64 + j * 16 + (lane & 15)) * LDK + kidx]);
#pragma unroll
            for (int i = 0; i < 4; ++i)
#pragma unroll
                for (int j = 0; j < 4; ++j)
                    acc[i][j] = __builtin_amdgcn_mfma_f32_16x16x32_bf16(afv[i], bfv[j], acc[i][j], 0, 0, 0);
        }
    }

    const int orow_base = m0 + wr * 64 + ((lane >> 4) << 2);
    const int ocol_base = n0 + wc * 64 + (lane & 15);
#pragma unroll
    for (int j = 0; j < 4; ++j) {
        const float bv = bias[ocol_base + j * 16];
#pragma unroll
        for (int i = 0; i < 4; ++i) {
#pragma unroll
            for (int q = 0; q < 4; ++q) {
                out[(size_t)(orow_base + i * 16 + q) * OUT_F + (ocol_base + j * 16)] =
                    acc[i][j][q] + bv;
            }
        }
    }
}

// ---------------------------------------------------------------------------
extern "C" void kernel_launch(void* const* d_in, const int* in_sizes, int n_in,
                              void* d_out, int out_size, void* d_ws, size_t ws_size,
                              hipStream_t stream) {
    const float* x      = (const float*)d_in[0];
    const int*   qw     = (const int*)d_in[1];
    const float* scales = (const float*)d_in[2];
    const float* zeros  = (const float*)d_in[3];
    const float* bias   = (const float*)d_in[4];
    float* out = (float*)d_out;

    const size_t wt_bytes = (size_t)OUT_F * IN_F * sizeof(unsigned short);   // 90.2 MB
    const size_t xb_bytes = (size_t)M_TOTAL * IN_F * sizeof(unsigned short); // 67.1 MB

    if (ws_size >= wt_bytes + xb_bytes) {
        unsigned short* wt = (unsigned short*)d_ws;
        unsigned short* xb = (unsigned short*)((char*)d_ws + wt_bytes);
        convert_x_frag_kernel<<<dim3(M_TOTAL / 32, 8), 256, 0, stream>>>(x, xb);
        dequant_w_frag_kernel<<<dim3(OUT_F / 256, IN_F / 32), 256, 0, stream>>>(qw, scales, zeros, wt);
        gemm_8phase<<<(M_TOTAL / 256) * (OUT_F / 256), 512, 0, stream>>>(xb, wt, bias, out);
    } else if (ws_size >= wt_bytes) {
        unsigned short* wt = (unsigned short*)d_ws;
        dequant_w_rowmajor_kernel<<<dim3(OUT_F / 256, IN_F / 32), 256, 0, stream>>>(qw, scales, zeros, wt);
        gemm_kernel<true><<<(M_TOTAL / 128) * (OUT_F / 128), 256, 0, stream>>>(x, wt, qw, scales, zeros, bias, out);
    } else {
        gemm_kernel<false><<<(M_TOTAL / 128) * (OUT_F / 128), 256, 0, stream>>>(x, nullptr, qw, scales, zeros, bias, out);
    }
}

// Round 9
// 719.516 us; speedup vs baseline: 1.2332x; 1.0089x over previous
//
#include <hip/hip_runtime.h>
#include <hip/hip_bf16.h>

#define IN_F 4096
#define OUT_F 11008
#define GSIZE 128
#define M_TOTAL 8192

typedef float f32x4 __attribute__((ext_vector_type(4)));
typedef float f32x16 __attribute__((ext_vector_type(16)));
typedef unsigned short u16x8 __attribute__((ext_vector_type(8)));
typedef unsigned int u32x4 __attribute__((ext_vector_type(4)));
typedef __bf16 bf16x8 __attribute__((ext_vector_type(8)));

#define ASG __attribute__((address_space(1)))
#define ASL __attribute__((address_space(3)))

__device__ __forceinline__ unsigned short f2bf(float f) {
    union { float f; unsigned int u; } v;
    v.f = f;
    unsigned int u = v.u;
    unsigned int r = (u + 0x7fffu + ((u >> 16) & 1u)) >> 16;
    return (unsigned short)r;
}

// ---------------------------------------------------------------------------
// Fragment-subtile global layout (matches MFMA 32x32x16 operand order):
//   subtile (f, kf) = 32 rows x 16 k, 1024 B at ((f * (K/16) + kf) * 1024).
//   lane l = (q2*32 + r): holds elem[row = f*32 + r][k = kf*16 + q2*8 .. +8].
// A staging instruction reads lane*16 -> 1024 CONTIGUOUS bytes (coalesced),
// writes linear LDS; ds_read fragment layout unchanged.
// ---------------------------------------------------------------------------

// Pass 0: x fp32 [M][K] -> xb fragment order [M/32][K/16][64][8].
__global__ void convert_x_frag_kernel(const float* __restrict__ x,
                                      unsigned short* __restrict__ xb) {
    const int mf = blockIdx.x;            // 0..255
    const int r  = threadIdx.x >> 3;      // 0..31
    const int kb = (threadIdx.x & 7) * 8; // 0..56
    const int k0 = blockIdx.y * 512;
    const float* src = x + (size_t)(mf * 32 + r) * IN_F;
    unsigned short* dst = xb + (size_t)mf * (IN_F / 16) * 512;
#pragma unroll
    for (int kk = 0; kk < 512; kk += 64) {
        const int k = k0 + kk + kb;
        f32x4 a = *(const f32x4*)(src + k);
        f32x4 b = *(const f32x4*)(src + k + 4);
        u16x8 v;
#pragma unroll
        for (int e = 0; e < 4; ++e) {
            v[e]     = f2bf(a[e]);
            v[e + 4] = f2bf(b[e]);
        }
        const int kf = k >> 4, q2 = (k >> 3) & 1;
        *(u16x8*)(dst + (size_t)kf * 512 + (q2 * 32 + r) * 8) = v;
    }
}

// Pass 1: int4 weights -> wt fragment order [N/32][K/16][64][8].
__global__ void dequant_w_frag_kernel(const int* __restrict__ qw,
                                      const float* __restrict__ scales,
                                      const float* __restrict__ zeros,
                                      unsigned short* __restrict__ wt) {
    const int n  = blockIdx.x * 256 + threadIdx.x;   // 0..11007
    const int k0 = blockIdx.y * 32;
    const int g  = k0 >> 7;
    const float s = scales[(size_t)g * OUT_F + n];
    const float z = zeros[(size_t)g * OUT_F + n];

    unsigned short outv[32];
#pragma unroll
    for (int i = 0; i < 16; ++i) {
        int q = qw[(size_t)(k0 / 2 + i) * OUT_F + n];
        float lo = (float)((q & 15) - 8) * s + z;        // even k = low nibble
        float hi = (float)(((q >> 4) & 15) - 8) * s + z; // odd k  = high nibble
        outv[2 * i]     = f2bf(lo);
        outv[2 * i + 1] = f2bf(hi);
    }
    const int nf = n >> 5, r32 = n & 31;
    unsigned short* base = wt + (size_t)nf * (IN_F / 16) * 512 +
                           (size_t)(k0 >> 4) * 512;
    const u16x8* sv = (const u16x8*)outv;
#pragma unroll
    for (int c = 0; c < 4; ++c)   // chunk c: k = k0 + c*8 .. +8
        *(u16x8*)(base + (c >> 1) * 512 + ((c & 1) * 32 + r32) * 8) = sv[c];
}

// Pass 1b (fallback path): row-major W^T bf16 [OUT_F][IN_F].
__global__ void dequant_w_rowmajor_kernel(const int* __restrict__ qw,
                                          const float* __restrict__ scales,
                                          const float* __restrict__ zeros,
                                          unsigned short* __restrict__ wt) {
    const int n  = blockIdx.x * 256 + threadIdx.x;
    const int k0 = blockIdx.y * 32;
    const int g  = k0 >> 7;
    const float s = scales[(size_t)g * OUT_F + n];
    const float z = zeros[(size_t)g * OUT_F + n];

    unsigned short outv[32];
#pragma unroll
    for (int i = 0; i < 16; ++i) {
        int q = qw[(size_t)(k0 / 2 + i) * OUT_F + n];
        float lo = (float)((q & 15) - 8) * s + z;
        float hi = (float)(((q >> 4) & 15) - 8) * s + z;
        outv[2 * i]     = f2bf(lo);
        outv[2 * i + 1] = f2bf(hi);
    }
    u16x8* dst = (u16x8*)(wt + (size_t)n * IN_F + k0);
    const u16x8* src = (const u16x8*)outv;
#pragma unroll
    for (int i = 0; i < 4; ++i) dst[i] = src[i];
}

// ---------------------------------------------------------------------------
// Pass 2: 256x256 bf16 GEMM, mfma_f32_32x32x16, round-8 zoned schedule
// (PASSING), with COALESCED staging from fragment-order global operands.
// Round-9 delta: NON-TEMPORAL epilogue stores — the 360 MB fp32 output
// stream was write-allocating in L3 and evicting the 157 MB operand set,
// causing 1.5 GB/dispatch HBM re-fetch (~2160 cyc/tile of HBM stall).
// Zones per tile t (buf p), 4 fenced barriers:
//  Z0 = [QUAD11(prev); READ_A0->afH0, READ_BLO->bfE; STG A1(t+1)->!p]
//  Z1 = [QUAD00; READ_BHI->bfO; STG B-G0(t+2)->p]
//  Z2 = [QUAD01; READ_A1->afH1; STG B-G1(t+2)->p]
//  Z3 = [QUAD10; STG A0(t+2)->p; vmcnt(6)]
// WAR/RAW identical to rounds 7/8 (passing).
// ---------------------------------------------------------------------------
__global__ __launch_bounds__(512, 1)
void gemm_8phase(const unsigned short* __restrict__ xb,   // frag order
                 const unsigned short* __restrict__ wt,   // frag order
                 const float* __restrict__ bias,
                 float* __restrict__ out) {
    constexpr int NT = IN_F / 64;  // 64 K-tiles
    constexpr int NKF = IN_F / 16; // 256 k-frags
    __shared__ __attribute__((aligned(128))) unsigned short lds[65536]; // 128 KiB

    constexpr int NB_N = OUT_F / 256;             // 43
    constexpr int NWG  = (M_TOTAL / 256) * NB_N;  // 1376 (divisible by 8)
    constexpr int CPX  = NWG / 8;                 // 172
    const int wg = ((int)blockIdx.x % 8) * CPX + (int)blockIdx.x / 8;
    const int m0 = (wg / NB_N) * 256;
    const int n0 = (wg % NB_N) * 256;

    const int tid  = threadIdx.x;
    const int lane = tid & 63;
    const int wave = tid >> 6;       // 0..7
    const int wr = wave >> 2;        // 0..1  (M)
    const int wc = wave & 3;         // 0..3  (N)
    const int r32 = lane & 31;
    const int q2  = lane >> 5;

    const ASG char* xbc = (const ASG char*)xb;
    const ASG char* wtc = (const ASG char*)wt;
    ASL char* ldsc = (ASL char*)lds;

    // ---- staging streams: per-thread 32-bit global byte offsets into the
    // fragment-order arrays (+4096 B per tile), wave-uniform LDS dests.
    const int mfb = m0 >> 5;   // base m-frag
    const int nfb = n0 >> 5;   // base n-frag
    unsigned int oA[4], oB[4];
    int dA[4], dB[4];
#pragma unroll
    for (int H = 0; H < 2; ++H)
#pragma unroll
        for (int i = 0; i < 2; ++i) {
            const int s = i * 8 + wave;
            const int rf = s >> 2, kc = s & 3;
            oA[H * 2 + i] = (unsigned int)(((mfb + H * 4 + rf) * NKF + kc) * 1024 +
                                           lane * 16);
            dA[H * 2 + i] = (H * 16 + s) * 1024;
        }
#pragma unroll
    for (int G = 0; G < 2; ++G)
#pragma unroll
        for (int i = 0; i < 2; ++i) {
            const int s = i * 8 + wave;
            const int cf = (s >> 2) * 2 + G, kc = s & 3;
            oB[G * 2 + i] = (unsigned int)(((nfb + cf) * NKF + kc) * 1024 +
                                           lane * 16);
            dB[G * 2 + i] = 32768 + (cf * 4 + kc) * 1024;
        }

#define STG_A(H, P)                                                            \
    do {                                                                       \
        _Pragma("unroll") for (int _i = 0; _i < 2; ++_i)                       \
            __builtin_amdgcn_global_load_lds(                                  \
                (ASG const unsigned int*)(xbc + oA[(H) * 2 + _i]),             \
                (ASL unsigned int*)(ldsc + dA[(H) * 2 + _i] + (P) * 65536),    \
                16, 0, 0);                                                     \
    } while (0)
#define STG_BG(G, P)                                                           \
    do {                                                                       \
        _Pragma("unroll") for (int _i = 0; _i < 2; ++_i)                       \
            __builtin_amdgcn_global_load_lds(                                  \
                (ASG const unsigned int*)(wtc + oB[(G) * 2 + _i]),             \
                (ASL unsigned int*)(ldsc + dB[(G) * 2 + _i] + (P) * 65536),    \
                16, 0, 0);                                                     \
    } while (0)
#define ADV_A(H) do { oA[(H)*2] += 4096; oA[(H)*2+1] += 4096; } while (0)
#define ADV_BG(G) do { oB[(G)*2] += 4096; oB[(G)*2+1] += 4096; } while (0)

#define BAR()                                                                  \
    do {                                                                       \
        __builtin_amdgcn_sched_barrier(0);                                     \
        __builtin_amdgcn_s_barrier();                                          \
        __builtin_amdgcn_sched_barrier(0);                                     \
    } while (0)

    bf16x8 afH0[2][4], afH1[2][4];
    bf16x8 bfE[4], bfO[4];
    f32x16 acc[4][2];
#pragma unroll
    for (int i = 0; i < 4; ++i)
#pragma unroll
        for (int j = 0; j < 2; ++j) acc[i][j] = (f32x16)0.0f;

#define READ_A0(P)                                                             \
    do {                                                                       \
        const unsigned short* _ab = lds + (P) * 32768 + lane * 8;              \
        _Pragma("unroll") for (int _m = 0; _m < 2; ++_m)                       \
        _Pragma("unroll") for (int _kc = 0; _kc < 4; ++_kc)                    \
            afH0[_m][_kc] = *(const bf16x8*)(_ab +                             \
                (((wr * 4 + _m) * 4 + _kc) << 9));                             \
    } while (0)
#define READ_A1(P)                                                             \
    do {                                                                       \
        const unsigned short* _ab = lds + (P) * 32768 + lane * 8;              \
        _Pragma("unroll") for (int _m = 0; _m < 2; ++_m)                       \
        _Pragma("unroll") for (int _kc = 0; _kc < 4; ++_kc)                    \
            afH1[_m][_kc] = *(const bf16x8*)(_ab +                             \
                (((wr * 4 + 2 + _m) * 4 + _kc) << 9));                         \
    } while (0)
#define READ_BLO(P)                                                            \
    do {                                                                       \
        const unsigned short* _bb = lds + (P) * 32768 + 16384 + lane * 8;      \
        _Pragma("unroll") for (int _kc = 0; _kc < 4; ++_kc)                    \
            bfE[_kc] = *(const bf16x8*)(_bb +                                  \
                (((wc * 2) * 4 + _kc) << 9));                                  \
    } while (0)
#define READ_BHI(P)                                                            \
    do {                                                                       \
        const unsigned short* _bb = lds + (P) * 32768 + 16384 + lane * 8;      \
        _Pragma("unroll") for (int _kc = 0; _kc < 4; ++_kc)                    \
            bfO[_kc] = *(const bf16x8*)(_bb +                                  \
                (((wc * 2 + 1) * 4 + _kc) << 9));                              \
    } while (0)

#define QUADX(AF, BF, MH, NH)                                                  \
    do {                                                                       \
        __builtin_amdgcn_s_setprio(1);                                         \
        _Pragma("unroll") for (int _m = 0; _m < 2; ++_m)                       \
        _Pragma("unroll") for (int _kc = 0; _kc < 4; ++_kc)                    \
            acc[(MH) * 2 + _m][(NH)] =                                         \
                __builtin_amdgcn_mfma_f32_32x32x16_bf16(                       \
                    AF[_m][_kc], BF[_kc], acc[(MH) * 2 + _m][(NH)], 0, 0, 0);  \
        __builtin_amdgcn_s_setprio(0);                                         \
    } while (0)

    // ---- prologue: tile0 {BG0,BG1,A0,A1}, tile1 {BG0,BG1,A0}; 6 in flight.
    STG_BG(0, 0); ADV_BG(0);
    STG_BG(1, 0); ADV_BG(1);
    STG_A(0, 0);  ADV_A(0);
    STG_A(1, 0);  ADV_A(1);    // A1 stream -> T=1
    STG_BG(0, 1); ADV_BG(0);   // -> T=2
    STG_BG(1, 1); ADV_BG(1);   // -> T=2
    STG_A(0, 1);  ADV_A(0);    // -> T=2
    __builtin_amdgcn_sched_barrier(0);
    asm volatile("s_waitcnt vmcnt(6)" ::: "memory");  // tile0 resident
    BAR();

#pragma unroll 1
    for (int tt = 0; tt < NT; tt += 2) {
        const bool g2 = (tt + 2 < NT);
        const bool g3 = (tt + 3 < NT);
        // ================= tile tt (buf 0) =================
        // Z0
        READ_A0(0);
        READ_BLO(0);
        STG_A(1, 1); ADV_A(1);                // A1(tt+1) -> buf1
        BAR();
        // Z1
        QUADX(afH0, bfE, 0, 0);
        READ_BHI(0);
        if (g2) STG_BG(0, 0);
        ADV_BG(0);                            // B-G0(tt+2) -> buf0
        BAR();
        // Z2
        QUADX(afH0, bfO, 0, 1);
        READ_A1(0);
        if (g2) STG_BG(1, 0);
        ADV_BG(1);                            // B-G1(tt+2) -> buf0
        BAR();
        // Z3
        QUADX(afH1, bfE, 1, 0);
        if (g2) STG_A(0, 0);
        ADV_A(0);                             // A0(tt+2) -> buf0
        __builtin_amdgcn_sched_barrier(0);
        if (tt < NT - 2) {
            asm volatile("s_waitcnt vmcnt(6)" ::: "memory");
        } else {
            asm volatile("s_waitcnt vmcnt(0)" ::: "memory");
        }
        BAR();
        QUADX(afH1, bfO, 1, 1);
        // ================= tile tt+1 (buf 1) =================
        // Z0
        READ_A0(1);
        READ_BLO(1);
        if (g2) STG_A(1, 0);
        ADV_A(1);                             // A1(tt+2) -> buf0
        BAR();
        // Z1
        QUADX(afH0, bfE, 0, 0);
        READ_BHI(1);
        if (g3) STG_BG(0, 1);
        ADV_BG(0);                            // B-G0(tt+3) -> buf1
        BAR();
        // Z2
        QUADX(afH0, bfO, 0, 1);
        READ_A1(1);
        if (g3) STG_BG(1, 1);
        ADV_BG(1);                            // B-G1(tt+3) -> buf1
        BAR();
        // Z3
        QUADX(afH1, bfE, 1, 0);
        if (g3) STG_A(0, 1);
        ADV_A(0);                             // A0(tt+3) -> buf1
        __builtin_amdgcn_sched_barrier(0);
        if (tt + 1 < NT - 2) {
            asm volatile("s_waitcnt vmcnt(6)" ::: "memory");
        } else {
            asm volatile("s_waitcnt vmcnt(0)" ::: "memory");
        }
        BAR();
        QUADX(afH1, bfO, 1, 1);
    }

    // ---- epilogue: 32x32 C/D layout col = lane&31,
    //      row = (reg&3) + 8*(reg>>2) + 4*(lane>>5)
    // NON-TEMPORAL stores: output is write-once; keep L3 for the operands.
#pragma unroll
    for (int nf = 0; nf < 2; ++nf) {
        const int col = n0 + wc * 64 + nf * 32 + r32;
        const float bv = bias[col];
#pragma unroll
        for (int mf = 0; mf < 4; ++mf) {
            const int row0 = m0 + wr * 128 + mf * 32 + q2 * 4;
#pragma unroll
            for (int r = 0; r < 16; ++r) {
                const int row = row0 + (r & 3) + ((r >> 2) << 3);
                __builtin_nontemporal_store(acc[mf][nf][r] + bv,
                                            &out[(size_t)row * OUT_F + col]);
            }
        }
    }
#undef STG_A
#undef STG_BG
#undef ADV_A
#undef ADV_BG
#undef BAR
#undef READ_A0
#undef READ_A1
#undef READ_BLO
#undef READ_BHI
#undef QUADX
}

// ---------------------------------------------------------------------------
// Fallback GEMM (reg-staged 128x128, row-major operands), for small ws.
// ---------------------------------------------------------------------------
template <bool PREW>
__global__ __launch_bounds__(256, 2)
void gemm_kernel(const float* __restrict__ x,
                 const unsigned short* __restrict__ wt,
                 const int* __restrict__ qw,
                 const float* __restrict__ scales,
                 const float* __restrict__ zeros,
                 const float* __restrict__ bias,
                 float* __restrict__ out) {
    constexpr int BM = 128, BN = 128, BK = 64;
    constexpr int LDK = BK + 8;
    constexpr int NT = IN_F / BK;

    __shared__ unsigned short As[BM * LDK];
    __shared__ unsigned short Bs[BN * LDK];

    const int bid = blockIdx.x;
    constexpr int NB_N = OUT_F / BN;
    const int m0 = (bid / NB_N) * BM;
    const int n0 = (bid % NB_N) * BN;

    const int tid  = threadIdx.x;
    const int lane = tid & 63;
    const int wave = tid >> 6;
    const int wr = wave >> 1, wc = wave & 1;

    const int st_row = tid >> 3;
    const int st_col = (tid & 7) * 8;

    f32x4 areg[4][2];
    u32x4 breg[4];
    int   qreg[16];
    float s_, z_;
    const int b_n  = tid & 127;
    const int b_kp = (tid >> 7) * 16;

    auto load_tile = [&](int kt) {
        {
            const float* base = x + (size_t)m0 * IN_F + (size_t)kt * BK + st_col;
#pragma unroll
            for (int p = 0; p < 4; ++p) {
                const float* rp = base + (size_t)(p * 32 + st_row) * IN_F;
                areg[p][0] = *(const f32x4*)rp;
                areg[p][1] = *(const f32x4*)(rp + 4);
            }
        }
        if constexpr (PREW) {
            const unsigned short* base = wt + (size_t)n0 * IN_F + (size_t)kt * BK + st_col;
#pragma unroll
            for (int p = 0; p < 4; ++p)
                breg[p] = *(const u32x4*)(base + (size_t)(p * 32 + st_row) * IN_F);
        } else {
            const int kp0 = kt * (BK / 2) + b_kp;
#pragma unroll
            for (int i = 0; i < 16; ++i)
                qreg[i] = qw[(size_t)(kp0 + i) * OUT_F + n0 + b_n];
            const int g = (kt * BK) >> 7;
            s_ = scales[(size_t)g * OUT_F + n0 + b_n];
            z_ = zeros[(size_t)g * OUT_F + n0 + b_n];
        }
    };

    auto write_lds = [&]() {
#pragma unroll
        for (int p = 0; p < 4; ++p) {
            u16x8 v;
#pragma unroll
            for (int e = 0; e < 4; ++e) {
                v[e]     = f2bf(areg[p][0][e]);
                v[e + 4] = f2bf(areg[p][1][e]);
            }
            *(u16x8*)(&As[(p * 32 + st_row) * LDK + st_col]) = v;
        }
        if constexpr (PREW) {
#pragma unroll
            for (int p = 0; p < 4; ++p)
                *(u32x4*)(&Bs[(p * 32 + st_row) * LDK + st_col]) = breg[p];
        } else {
            unsigned short tmp[32];
#pragma unroll
            for (int i = 0; i < 16; ++i) {
                int q = qreg[i];
                tmp[2 * i]     = f2bf((float)((q & 15) - 8) * s_ + z_);
                tmp[2 * i + 1] = f2bf((float)(((q >> 4) & 15) - 8) * s_ + z_);
            }
            const u16x8* srcv = (const u16x8*)tmp;
#pragma unroll
            for (int i = 0; i < 4; ++i)
                *(u16x8*)(&Bs[b_n * LDK + 2 * b_kp + 8 * i]) = srcv[i];
        }
    };

    f32x4 acc[4][4];
#pragma unroll
    for (int i = 0; i < 4; ++i)
#pragma unroll
        for (int j = 0; j < 4; ++j) acc[i][j] = (f32x4)0.0f;

    load_tile(0);

#pragma unroll 1
    for (int kt = 0; kt < NT; ++kt) {
        __syncthreads();
        write_lds();
        __syncthreads();
        if (kt + 1 < NT) load_tile(kt + 1);

#pragma unroll
        for (int kk = 0; kk < 2; ++kk) {
            const int kidx = kk * 32 + ((lane >> 4) << 3);
            bf16x8 afv[4], bfv[4];
#pragma unroll
            for (int i = 0; i < 4; ++i)
                afv[i] = *(const bf16x8*)(&As[(wr * 64 + i * 16 + (lane & 15)) * LDK + kidx]);
#pragma unroll
            for (int j = 0; j < 4; ++j)
                bfv[j] = *(const bf16x8*)(&Bs[(wc * 64 + j * 16 + (lane & 15)) * LDK + kidx]);
#pragma unroll
            for (int i = 0; i < 4; ++i)
#pragma unroll
                for (int j = 0; j < 4; ++j)
                    acc[i][j] = __builtin_amdgcn_mfma_f32_16x16x32_bf16(afv[i], bfv[j], acc[i][j], 0, 0, 0);
        }
    }

    const int orow_base = m0 + wr * 64 + ((lane >> 4) << 2);
    const int ocol_base = n0 + wc * 64 + (lane & 15);
#pragma unroll
    for (int j = 0; j < 4; ++j) {
        const float bv = bias[ocol_base + j * 16];
#pragma unroll
        for (int i = 0; i < 4; ++i) {
#pragma unroll
            for (int q = 0; q < 4; ++q) {
                out[(size_t)(orow_base + i * 16 + q) * OUT_F + (ocol_base + j * 16)] =
                    acc[i][j][q] + bv;
            }
        }
    }
}

// ---------------------------------------------------------------------------
extern "C" void kernel_launch(void* const* d_in, const int* in_sizes, int n_in,
                              void* d_out, int out_size, void* d_ws, size_t ws_size,
                              hipStream_t stream) {
    const float* x      = (const float*)d_in[0];
    const int*   qw     = (const int*)d_in[1];
    const float* scales = (const float*)d_in[2];
    const float* zeros  = (const float*)d_in[3];
    const float* bias   = (const float*)d_in[4];
    float* out = (float*)d_out;

    const size_t wt_bytes = (size_t)OUT_F * IN_F * sizeof(unsigned short);   // 90.2 MB
    const size_t xb_bytes = (size_t)M_TOTAL * IN_F * sizeof(unsigned short); // 67.1 MB

    if (ws_size >= wt_bytes + xb_bytes) {
        unsigned short* wt = (unsigned short*)d_ws;
        unsigned short* xb = (unsigned short*)((char*)d_ws + wt_bytes);
        convert_x_frag_kernel<<<dim3(M_TOTAL / 32, 8), 256, 0, stream>>>(x, xb);
        dequant_w_frag_kernel<<<dim3(OUT_F / 256, IN_F / 32), 256, 0, stream>>>(qw, scales, zeros, wt);
        gemm_8phase<<<(M_TOTAL / 256) * (OUT_F / 256), 512, 0, stream>>>(xb, wt, bias, out);
    } else if (ws_size >= wt_bytes) {
        unsigned short* wt = (unsigned short*)d_ws;
        dequant_w_rowmajor_kernel<<<dim3(OUT_F / 256, IN_F / 32), 256, 0, stream>>>(qw, scales, zeros, wt);
        gemm_kernel<true><<<(M_TOTAL / 128) * (OUT_F / 128), 256, 0, stream>>>(x, wt, qw, scales, zeros, bias, out);
    } else {
        gemm_kernel<false><<<(M_TOTAL / 128) * (OUT_F / 128), 256, 0, stream>>>(x, nullptr, qw, scales, zeros, bias, out);
    }
}